// Round 7
// baseline (250.345 us; speedup 1.0000x reference)
//
#include <hip/hip_runtime.h>

// ---------------------------------------------------------------------------
// DistillationLoss, round 7.
// MFMA split-bf16 d^2 (verified exact-enough in R5: absmax 0.0):
//   one v_mfma_f32_32x32x16_bf16 per 32x32 tile gives d^2 = aa + bb - 2 a.b.
// R6 changes (diagnosis: latency/occupancy-bound at 23% occ, z-phased grid):
//   1. Chamfer direction fusion: each tile's row-min -> A-side, col-min ->
//      B-side (LDS colmin + block flush). 4 min passes -> 2 fused passes.
//   2. Flat 1D grid, uniform work: 2048 fused + 1024 argmin + 64 edge blocks,
//      TR=1, 512-col chunks -> ~8 resident blocks/CU at VGPR<=64.
//   3. B-frag prefetch in fused loop.
// Packs needed: A-form(sv), B-form(tp, gp, tv) only.
// C/D layout: col=lane&31, row=(q&3)+8*(q>>2)+4*(lane>>5).
// 3 launches: init(pack) -> mega -> post(fused tail + final).
// ---------------------------------------------------------------------------

typedef short sh8 __attribute__((ext_vector_type(8)));
typedef float f32x16 __attribute__((ext_vector_type(16)));

#define BLK 256
#define CCT 16          // col-tiles per chunk = 512 cols
#define NCC 16          // col chunks (8192/512)
#define NRB 64          // row blocks (256 row-tiles / 4 waves)
#define NB_F (2 * NRB * NCC)   // 2048 fused blocks
#define NB_A (NRB * NCC)       // 1024 argmin blocks
#define NB_E 64                // edge blocks

__device__ __forceinline__ float wave_reduce_sum(float v) {
#pragma unroll
  for (int o = 32; o > 0; o >>= 1) v += __shfl_down(v, o, 64);
  return v;
}

// total-order float -> uint (monotone)
__device__ __forceinline__ unsigned flipf(float f) {
  unsigned b = __float_as_uint(f);
  return (b & 0x80000000u) ? ~b : (b | 0x80000000u);
}
__device__ __forceinline__ float unflipf(unsigned u) {
  unsigned b = (u & 0x80000000u) ? (u ^ 0x80000000u) : ~u;
  return __uint_as_float(b);
}

__device__ __forceinline__ unsigned short f2bf(float x) {  // RNE f32->bf16
  unsigned u = __float_as_uint(x);
  unsigned r = (u + 0x7FFFu + ((u >> 16) & 1u)) >> 16;
  return (unsigned short)r;
}
__device__ __forceinline__ float bf2f(unsigned short b) {
  return __uint_as_float(((unsigned)b) << 16);
}

// Pack point i into A-form and/or B-form fragment arrays (layout as R5,
// verified absmax 0.0). tile=i>>5, lane=i&31 holds k0-7, lane+32 k8-15.
__device__ void pack_pt(int i, float x, float y, float z, sh8* Ap, sh8* Bp) {
  float aa = fmaf(x, x, fmaf(y, y, z * z));
  unsigned short hx = f2bf(x), hy = f2bf(y), hz = f2bf(z);
  float lx = x - bf2f(hx), ly = y - bf2f(hy), lz = z - bf2f(hz);
  unsigned short haa = f2bf(aa);
  float laa = aa - bf2f(haa);
  const short ONE = (short)0x3F80;
  const int base = (i >> 5) * 64 + (i & 31);
  if (Ap) {
    unsigned short nhx = f2bf(-2.f * bf2f(hx)), nhy = f2bf(-2.f * bf2f(hy)),
                   nhz = f2bf(-2.f * bf2f(hz));
    unsigned short nlx = f2bf(-2.f * lx), nly = f2bf(-2.f * ly),
                   nlz = f2bf(-2.f * lz);
    sh8 lo, hi;
    lo[0] = (short)nhx; lo[1] = (short)nhy; lo[2] = (short)nhz;
    lo[3] = (short)nlx; lo[4] = (short)nly; lo[5] = (short)nlz;
    lo[6] = (short)nhx; lo[7] = (short)nhy;
    hi[0] = (short)nhz; hi[1] = (short)haa; hi[2] = (short)f2bf(laa);
    hi[3] = ONE; hi[4] = ONE; hi[5] = 0; hi[6] = 0; hi[7] = 0;
    Ap[base] = lo; Ap[base + 32] = hi;
  }
  if (Bp) {
    unsigned short lxb = f2bf(lx), lyb = f2bf(ly), lzb = f2bf(lz);
    sh8 lo, hi;
    lo[0] = (short)hx; lo[1] = (short)hy; lo[2] = (short)hz;
    lo[3] = (short)hx; lo[4] = (short)hy; lo[5] = (short)hz;
    lo[6] = (short)lxb; lo[7] = (short)lyb;
    hi[0] = (short)lzb; hi[1] = ONE; hi[2] = ONE;
    hi[3] = (short)haa; hi[4] = (short)f2bf(laa);
    hi[5] = 0; hi[6] = 0; hi[7] = 0;
    Bp[base] = lo; Bp[base + 32] = hi;
  }
}

__global__ void init_ws_kernel(sh8* __restrict__ Asv, sh8* __restrict__ Btp,
                               sh8* __restrict__ Bgp, sh8* __restrict__ Btv,
                               const float* __restrict__ sv,
                               const float* __restrict__ tp,
                               const float* __restrict__ gp,
                               const float* __restrict__ tv,
                               unsigned long long* __restrict__ min64, int n64,
                               unsigned* __restrict__ minbits, int nmin,
                               float* __restrict__ zr, int nz, int n) {
  const int stride = gridDim.x * blockDim.x;
  const int t0 = blockIdx.x * blockDim.x + threadIdx.x;
  for (int i = t0; i < n64; i += stride) min64[i] = ~0ull;
  for (int i = t0; i < nmin; i += stride) minbits[i] = 0xFF800000u;  // flip(+inf)
  for (int i = t0; i < nz; i += stride) zr[i] = 0.0f;                // also cnt=0
  for (int i = t0; i < n; i += stride) {
    pack_pt(i, sv[3 * i], sv[3 * i + 1], sv[3 * i + 2], Asv, (sh8*)0);
    pack_pt(i, tp[3 * i], tp[3 * i + 1], tp[3 * i + 2], (sh8*)0, Btp);
    pack_pt(i, gp[3 * i], gp[3 * i + 1], gp[3 * i + 2], (sh8*)0, Bgp);
    pack_pt(i, tv[3 * i], tv[3 * i + 1], tv[3 * i + 2], (sh8*)0, Btv);
  }
}

struct Desc {
  const sh8 *Asv, *Btp, *Bgp, *Btv;
  unsigned *minA_tp, *minB_tp, *minA_gt, *minB_gt;
  unsigned long long* min64;
  const int* fc; int f;
  const float* sv;
  float* nbr; float* deg; float* acc;
};

// Flat grid: [0,NB_F) fused chamfer, [NB_F,NB_F+NB_A) argmin, rest edge.
__global__ void __launch_bounds__(BLK, 8) mega_kernel(Desc d) {
  const int t = threadIdx.x;
  const int bid = blockIdx.x;
  const int wave = t >> 6, lane = t & 63;
  const float INF = __int_as_float(0x7f800000);

  if (bid >= NB_F + NB_A) {
    // ---- edge + laplacian accumulation ----
    const int nE = 3 * d.f;
    const int stride = NB_E * BLK;
    float es = 0.f;
    for (int e = (bid - NB_F - NB_A) * BLK + t; e < nE; e += stride) {
      int a, b;
      if (e < d.f)          { a = d.fc[3 * e + 0];  b = d.fc[3 * e + 1]; }
      else if (e < 2 * d.f) { int q = e - d.f;     a = d.fc[3 * q + 1]; b = d.fc[3 * q + 2]; }
      else                  { int q = e - 2 * d.f; a = d.fc[3 * q + 2]; b = d.fc[3 * q + 0]; }
      float ax = d.sv[3 * a], ay = d.sv[3 * a + 1], az = d.sv[3 * a + 2];
      float bx = d.sv[3 * b], by = d.sv[3 * b + 1], bz = d.sv[3 * b + 2];
      float dx = ax - bx, dy = ay - by, dz = az - bz;
      es += fmaf(dx, dx, fmaf(dy, dy, dz * dz));
      atomicAdd(&d.nbr[3 * a + 0], bx);
      atomicAdd(&d.nbr[3 * a + 1], by);
      atomicAdd(&d.nbr[3 * a + 2], bz);
      atomicAdd(&d.nbr[3 * b + 0], ax);
      atomicAdd(&d.nbr[3 * b + 1], ay);
      atomicAdd(&d.nbr[3 * b + 2], az);
      atomicAdd(&d.deg[a], 1.0f);
      atomicAdd(&d.deg[b], 1.0f);
    }
    es = wave_reduce_sum(es);
    if ((t & 63) == 0) atomicAdd(&d.acc[4], es);
    return;
  }

  f32x16 zc;
#pragma unroll
  for (int q = 0; q < 16; ++q) zc[q] = 0.f;

  if (bid < NB_F) {
    // ---- fused chamfer pass: row-min AND col-min from each tile ----
    __shared__ unsigned colmin[CCT * 32];
    const int fsel = bid >> 10;                 // 0: (sv,tp)  1: (sv,gp)
    const int rem = bid & 1023;
    const int rb = rem >> 4, cc = rem & 15;
    const sh8* __restrict__ Ap = d.Asv;
    const sh8* __restrict__ Bp = fsel ? d.Bgp : d.Btp;
    unsigned* __restrict__ outR = fsel ? d.minA_gt : d.minA_tp;
    unsigned* __restrict__ outC = fsel ? d.minB_gt : d.minB_tp;

    for (int i = t; i < CCT * 32; i += BLK) colmin[i] = 0xFFFFFFFFu;
    __syncthreads();

    const int rt = rb * 4 + wave;
    sh8 af = Ap[(size_t)rt * 64 + lane];
    const int jt0 = cc * CCT;
    sh8 bf = Bp[(size_t)jt0 * 64 + lane];
    f32x16 r;
#pragma unroll
    for (int q = 0; q < 16; ++q) r[q] = INF;

#pragma unroll 4
    for (int jt = 0; jt < CCT; ++jt) {
      int jn = (jt + 1 < CCT) ? (jt + 1) : jt;          // clamped prefetch
      sh8 bfn = Bp[(size_t)(jt0 + jn) * 64 + lane];
      f32x16 c = __builtin_amdgcn_mfma_f32_32x32x16_bf16(af, bf, zc, 0, 0, 0);
      r = __builtin_elementwise_min(r, c);
      float cv = c[0];
#pragma unroll
      for (int q = 1; q < 16; ++q) cv = fminf(cv, c[q]);
      cv = fminf(cv, __shfl_xor(cv, 32));
      if (lane < 32) atomicMin(&colmin[(jt << 5) | lane], flipf(cv));
      bf = bfn;
    }

    unsigned* __restrict__ outRow = outR;
#pragma unroll
    for (int q = 0; q < 16; ++q) {
      float v = r[q];
      v = fminf(v, __shfl_xor(v, 1));
      v = fminf(v, __shfl_xor(v, 2));
      v = fminf(v, __shfl_xor(v, 4));
      v = fminf(v, __shfl_xor(v, 8));
      v = fminf(v, __shfl_xor(v, 16));
      if ((lane & 31) == 0) {
        int row = rt * 32 + (q & 3) + 8 * (q >> 2) + 4 * (lane >> 5);
        atomicMin(outRow + row, flipf(v));
      }
    }
    __syncthreads();
    for (int i = t; i < CCT * 32; i += BLK)
      atomicMin(outC + cc * (CCT * 32) + i, colmin[i]);
  } else {
    // ---- argmin pass (sv rows x tv cols) ----
    const int rem = bid - NB_F;
    const int rb = rem >> 4, cc = rem & 15;
    const int rt = rb * 4 + wave;
    const sh8* __restrict__ Ap = d.Asv;
    const sh8* __restrict__ Bp = d.Btv;
    sh8 af = Ap[(size_t)rt * 64 + lane];
    const int jt0 = cc * CCT;
    f32x16 m;
    float idx[16];
#pragma unroll
    for (int q = 0; q < 16; ++q) { m[q] = INF; idx[q] = 0.f; }
#pragma unroll 2
    for (int jt = 0; jt < CCT; ++jt) {
      sh8 bf = Bp[(size_t)(jt0 + jt) * 64 + lane];
      f32x16 c = __builtin_amdgcn_mfma_f32_32x32x16_bf16(af, bf, zc, 0, 0, 0);
      float colf = (float)((jt0 + jt) * 32 + (lane & 31));
#pragma unroll
      for (int q = 0; q < 16; ++q) {
        bool cm = c[q] < m[q];
        m[q] = cm ? c[q] : m[q];
        idx[q] = cm ? colf : idx[q];
      }
    }
    unsigned long long* __restrict__ out = d.min64;
#pragma unroll
    for (int q = 0; q < 16; ++q) {
      float v = m[q], ix = idx[q];
#pragma unroll
      for (int s = 0; s < 5; ++s) {
        int msk = 1 << s;
        float ov = __shfl_xor(v, msk);
        float oi = __shfl_xor(ix, msk);
        bool take = (ov < v) || (ov == v && oi < ix);
        v = take ? ov : v;
        ix = take ? oi : ix;
      }
      if ((lane & 31) == 0) {
        int row = rt * 32 + (q & 3) + 8 * (q >> 2) + 4 * (lane >> 5);
        unsigned long long packed =
            ((unsigned long long)flipf(v) << 32) | (unsigned)(int)ix;
        atomicMin(out + row, packed);
      }
    }
  }
}

// Fused tail. blockIdx.y: 0 smooth->acc[5], 1 normal->acc[6], 2-5 sqrt-sums
// ->acc[0..3]. Last block (ticket) computes the final scalar.
__global__ void __launch_bounds__(BLK) post_kernel(
    const float* __restrict__ sv, const float* __restrict__ sn,
    const float* __restrict__ tn,
    const float* __restrict__ nbr, const float* __restrict__ deg,
    const unsigned* __restrict__ minbase,
    const unsigned long long* __restrict__ min64,
    int n, int p, int g, int f, float* __restrict__ acc,
    int* __restrict__ cnt, float* __restrict__ out) {
  const int task = blockIdx.y;
  const int i = blockIdx.x * blockDim.x + threadIdx.x;
  float s = 0.f;
  int accIdx;
  if (task == 0) {
    accIdx = 5;
    if (i < n) {
      float dd = fmaxf(deg[i], 1.0f);
      float lx = nbr[3 * i + 0] / dd - sv[3 * i + 0];
      float ly = nbr[3 * i + 1] / dd - sv[3 * i + 1];
      float lz = nbr[3 * i + 2] / dd - sv[3 * i + 2];
      s = sqrtf(fmaf(lx, lx, fmaf(ly, ly, lz * lz)));
    }
  } else if (task == 1) {
    accIdx = 6;
    if (i < n) {
      int idx = (int)(min64[i] & 0xffffffffull);
      float sx = sn[3 * i], sy = sn[3 * i + 1], sz = sn[3 * i + 2];
      float tx = tn[3 * idx], ty = tn[3 * idx + 1], tz = tn[3 * idx + 2];
      float num = fmaf(sx, tx, fmaf(sy, ty, sz * tz));
      float ns = sqrtf(fmaf(sx, sx, fmaf(sy, sy, sz * sz)));
      float nt = sqrtf(fmaf(tx, tx, fmaf(ty, ty, tz * tz)));
      s = num / (fmaxf(ns, 1e-8f) * fmaxf(nt, 1e-8f));
    }
  } else {
    const int seg = task - 2;
    accIdx = seg;
    const int off = (seg == 0) ? 0 : (seg == 1) ? n : (seg == 2) ? (n + p) : (2 * n + p);
    const int cntN = (seg == 1) ? p : n;
    if (i < cntN) {
      float d2 = unflipf(minbase[off + i]);   // full d^2 from MFMA
      s = sqrtf(fmaxf(d2, 0.0f));
    }
  }
  s = wave_reduce_sum(s);
  if ((threadIdx.x & 63) == 0) atomicAdd(&acc[accIdx], s);

  __syncthreads();
  __threadfence();
  __shared__ int last;
  if (threadIdx.x == 0)
    last = (atomicAdd(cnt, 1) == (int)(gridDim.x * gridDim.y) - 1);
  __syncthreads();
  if (last && threadIdx.x == 0) {
    float a[7];
#pragma unroll
    for (int q = 0; q < 7; ++q) a[q] = atomicAdd(&acc[q], 0.0f);
    float lt = 0.5f * (a[0] / (float)n + a[1] / (float)p);
    float lg = 0.5f * (a[2] / (float)n + a[3] / (float)g);
    float chamfer = 0.7f * lt + 0.3f * lg;
    float edge = a[4] / (float)(3 * f);
    float smooth = a[5] / (float)n;
    float normal = 1.0f - a[6] / (float)n;
    out[0] = chamfer + 2.0f * edge + smooth + 0.5f * normal;
  }
}

extern "C" void kernel_launch(void* const* d_in, const int* in_sizes, int n_in,
                              void* d_out, int out_size, void* d_ws, size_t ws_size,
                              hipStream_t stream) {
  const float* sv = (const float*)d_in[0];
  const float* sn = (const float*)d_in[1];
  const float* tv = (const float*)d_in[2];
  const float* tn = (const float*)d_in[3];
  const float* tp = (const float*)d_in[4];
  const float* gp = (const float*)d_in[5];
  const int*   fc = (const int*)d_in[6];
  const int n = in_sizes[0] / 3;
  const int m = in_sizes[2] / 3;
  const int p = in_sizes[4] / 3;
  const int g = in_sizes[5] / 3;
  const int f = in_sizes[6] / 3;

  // ws layout: fragment packs (32 B per point per form), then scratch.
  char* w = (char*)d_ws;
  sh8* Asv = (sh8*)w; w += (size_t)n * 32;
  sh8* Btp = (sh8*)w; w += (size_t)p * 32;
  sh8* Bgp = (sh8*)w; w += (size_t)g * 32;
  sh8* Btv = (sh8*)w; w += (size_t)m * 32;
  unsigned long long* min64 = (unsigned long long*)w; w += (size_t)n * 8;
  unsigned* minbase = (unsigned*)w; w += (size_t)(n + p + n + g) * 4;
  float* nbr = (float*)w; w += (size_t)n * 3 * 4;   // zero region starts here
  float* deg = (float*)w; w += (size_t)n * 4;
  float* acc = (float*)w; w += 8 * 4;
  int* cnt = (int*)w;

  const int nmin = n + p + n + g;
  const int nz = n * 3 + n + 8 + 1;   // nbr, deg, acc, cnt

  init_ws_kernel<<<64, BLK, 0, stream>>>(Asv, Btp, Bgp, Btv, sv, tp, gp, tv,
                                         min64, n, minbase, nmin, nbr, nz, n);

  Desc d;
  d.Asv = Asv; d.Btp = Btp; d.Bgp = Bgp; d.Btv = Btv;
  d.minA_tp = minbase;
  d.minB_tp = minbase + n;
  d.minA_gt = minbase + n + p;
  d.minB_gt = minbase + 2 * n + p;
  d.min64 = min64;
  d.fc = fc; d.f = f; d.sv = sv;
  d.nbr = nbr; d.deg = deg; d.acc = acc;

  mega_kernel<<<NB_F + NB_A + NB_E, BLK, 0, stream>>>(d);

  dim3 tgrid((n + BLK - 1) / BLK, 6);
  post_kernel<<<tgrid, BLK, 0, stream>>>(sv, sn, tn, nbr, deg,
                                         minbase, min64, n, p, g, f,
                                         acc, cnt, (float*)d_out);
}

// Round 8
// 140.639 us; speedup vs baseline: 1.7801x; 1.7801x over previous
//
#include <hip/hip_runtime.h>

// ---------------------------------------------------------------------------
// DistillationLoss, round 8.
// Same structure as round 7 (MFMA split-bf16 d^2; direction-fused chamfer
// tiles: row-min + col-min from one tile; flat uniform grid; prefetch), with
// THE fix: no min-waves clamp in __launch_bounds__. Round 7's (BLK,8) forced
// VGPR=32 -> full spill of the f32x16 accumulators -> 680 MB scratch traffic
// (FETCH 217 MB / WRITE 446 MB) and 166 us. R6-style natural allocation is
// 64 VGPR, zero spill.
// 3 launches: init(pack) -> mega -> post(fused tail + final).
// ---------------------------------------------------------------------------

typedef short sh8 __attribute__((ext_vector_type(8)));
typedef float f32x16 __attribute__((ext_vector_type(16)));

#define BLK 256
#define CCT 16          // col-tiles per chunk = 512 cols
#define NCC 16          // col chunks (8192/512)
#define NRB 64          // row blocks (256 row-tiles / 4 waves)
#define NB_F (2 * NRB * NCC)   // 2048 fused blocks
#define NB_A (NRB * NCC)       // 1024 argmin blocks
#define NB_E 64                // edge blocks

__device__ __forceinline__ float wave_reduce_sum(float v) {
#pragma unroll
  for (int o = 32; o > 0; o >>= 1) v += __shfl_down(v, o, 64);
  return v;
}

// total-order float -> uint (monotone)
__device__ __forceinline__ unsigned flipf(float f) {
  unsigned b = __float_as_uint(f);
  return (b & 0x80000000u) ? ~b : (b | 0x80000000u);
}
__device__ __forceinline__ float unflipf(unsigned u) {
  unsigned b = (u & 0x80000000u) ? (u ^ 0x80000000u) : ~u;
  return __uint_as_float(b);
}

__device__ __forceinline__ unsigned short f2bf(float x) {  // RNE f32->bf16
  unsigned u = __float_as_uint(x);
  unsigned r = (u + 0x7FFFu + ((u >> 16) & 1u)) >> 16;
  return (unsigned short)r;
}
__device__ __forceinline__ float bf2f(unsigned short b) {
  return __uint_as_float(((unsigned)b) << 16);
}

// Pack point i into A-form and/or B-form fragment arrays (layout verified
// absmax 0.0 in R5/R6). tile=i>>5, lane=i&31 holds k0-7, lane+32 k8-15.
__device__ void pack_pt(int i, float x, float y, float z, sh8* Ap, sh8* Bp) {
  float aa = fmaf(x, x, fmaf(y, y, z * z));
  unsigned short hx = f2bf(x), hy = f2bf(y), hz = f2bf(z);
  float lx = x - bf2f(hx), ly = y - bf2f(hy), lz = z - bf2f(hz);
  unsigned short haa = f2bf(aa);
  float laa = aa - bf2f(haa);
  const short ONE = (short)0x3F80;
  const int base = (i >> 5) * 64 + (i & 31);
  if (Ap) {
    unsigned short nhx = f2bf(-2.f * bf2f(hx)), nhy = f2bf(-2.f * bf2f(hy)),
                   nhz = f2bf(-2.f * bf2f(hz));
    unsigned short nlx = f2bf(-2.f * lx), nly = f2bf(-2.f * ly),
                   nlz = f2bf(-2.f * lz);
    sh8 lo, hi;
    lo[0] = (short)nhx; lo[1] = (short)nhy; lo[2] = (short)nhz;
    lo[3] = (short)nlx; lo[4] = (short)nly; lo[5] = (short)nlz;
    lo[6] = (short)nhx; lo[7] = (short)nhy;
    hi[0] = (short)nhz; hi[1] = (short)haa; hi[2] = (short)f2bf(laa);
    hi[3] = ONE; hi[4] = ONE; hi[5] = 0; hi[6] = 0; hi[7] = 0;
    Ap[base] = lo; Ap[base + 32] = hi;
  }
  if (Bp) {
    unsigned short lxb = f2bf(lx), lyb = f2bf(ly), lzb = f2bf(lz);
    sh8 lo, hi;
    lo[0] = (short)hx; lo[1] = (short)hy; lo[2] = (short)hz;
    lo[3] = (short)hx; lo[4] = (short)hy; lo[5] = (short)hz;
    lo[6] = (short)lxb; lo[7] = (short)lyb;
    hi[0] = (short)lzb; hi[1] = ONE; hi[2] = ONE;
    hi[3] = (short)haa; hi[4] = (short)f2bf(laa);
    hi[5] = 0; hi[6] = 0; hi[7] = 0;
    Bp[base] = lo; Bp[base + 32] = hi;
  }
}

__global__ void init_ws_kernel(sh8* __restrict__ Asv, sh8* __restrict__ Btp,
                               sh8* __restrict__ Bgp, sh8* __restrict__ Btv,
                               const float* __restrict__ sv,
                               const float* __restrict__ tp,
                               const float* __restrict__ gp,
                               const float* __restrict__ tv,
                               unsigned long long* __restrict__ min64, int n64,
                               unsigned* __restrict__ minbits, int nmin,
                               float* __restrict__ zr, int nz, int n) {
  const int stride = gridDim.x * blockDim.x;
  const int t0 = blockIdx.x * blockDim.x + threadIdx.x;
  for (int i = t0; i < n64; i += stride) min64[i] = ~0ull;
  for (int i = t0; i < nmin; i += stride) minbits[i] = 0xFF800000u;  // flip(+inf)
  for (int i = t0; i < nz; i += stride) zr[i] = 0.0f;                // also cnt=0
  for (int i = t0; i < n; i += stride) {
    pack_pt(i, sv[3 * i], sv[3 * i + 1], sv[3 * i + 2], Asv, (sh8*)0);
    pack_pt(i, tp[3 * i], tp[3 * i + 1], tp[3 * i + 2], (sh8*)0, Btp);
    pack_pt(i, gp[3 * i], gp[3 * i + 1], gp[3 * i + 2], (sh8*)0, Bgp);
    pack_pt(i, tv[3 * i], tv[3 * i + 1], tv[3 * i + 2], (sh8*)0, Btv);
  }
}

struct Desc {
  const sh8 *Asv, *Btp, *Bgp, *Btv;
  unsigned *minA_tp, *minB_tp, *minA_gt, *minB_gt;
  unsigned long long* min64;
  const int* fc; int f;
  const float* sv;
  float* nbr; float* deg; float* acc;
};

// Flat grid: [0,NB_F) fused chamfer, [NB_F,NB_F+NB_A) argmin, rest edge.
// NOTE: no min-waves clamp — natural VGPR allocation (~64), zero spill.
__global__ void __launch_bounds__(BLK) mega_kernel(Desc d) {
  const int t = threadIdx.x;
  const int bid = blockIdx.x;
  const int wave = t >> 6, lane = t & 63;
  const float INF = __int_as_float(0x7f800000);

  if (bid >= NB_F + NB_A) {
    // ---- edge + laplacian accumulation ----
    const int nE = 3 * d.f;
    const int stride = NB_E * BLK;
    float es = 0.f;
    for (int e = (bid - NB_F - NB_A) * BLK + t; e < nE; e += stride) {
      int a, b;
      if (e < d.f)          { a = d.fc[3 * e + 0];  b = d.fc[3 * e + 1]; }
      else if (e < 2 * d.f) { int q = e - d.f;     a = d.fc[3 * q + 1]; b = d.fc[3 * q + 2]; }
      else                  { int q = e - 2 * d.f; a = d.fc[3 * q + 2]; b = d.fc[3 * q + 0]; }
      float ax = d.sv[3 * a], ay = d.sv[3 * a + 1], az = d.sv[3 * a + 2];
      float bx = d.sv[3 * b], by = d.sv[3 * b + 1], bz = d.sv[3 * b + 2];
      float dx = ax - bx, dy = ay - by, dz = az - bz;
      es += fmaf(dx, dx, fmaf(dy, dy, dz * dz));
      atomicAdd(&d.nbr[3 * a + 0], bx);
      atomicAdd(&d.nbr[3 * a + 1], by);
      atomicAdd(&d.nbr[3 * a + 2], bz);
      atomicAdd(&d.nbr[3 * b + 0], ax);
      atomicAdd(&d.nbr[3 * b + 1], ay);
      atomicAdd(&d.nbr[3 * b + 2], az);
      atomicAdd(&d.deg[a], 1.0f);
      atomicAdd(&d.deg[b], 1.0f);
    }
    es = wave_reduce_sum(es);
    if ((t & 63) == 0) atomicAdd(&d.acc[4], es);
    return;
  }

  f32x16 zc;
#pragma unroll
  for (int q = 0; q < 16; ++q) zc[q] = 0.f;

  if (bid < NB_F) {
    // ---- fused chamfer pass: row-min AND col-min from each tile ----
    __shared__ unsigned colmin[CCT * 32];
    const int fsel = bid >> 10;                 // 0: (sv,tp)  1: (sv,gp)
    const int rem = bid & 1023;
    const int rb = rem >> 4, cc = rem & 15;
    const sh8* __restrict__ Ap = d.Asv;
    const sh8* __restrict__ Bp = fsel ? d.Bgp : d.Btp;
    unsigned* __restrict__ outR = fsel ? d.minA_gt : d.minA_tp;
    unsigned* __restrict__ outC = fsel ? d.minB_gt : d.minB_tp;

    for (int i = t; i < CCT * 32; i += BLK) colmin[i] = 0xFFFFFFFFu;
    __syncthreads();

    const int rt = rb * 4 + wave;
    sh8 af = Ap[(size_t)rt * 64 + lane];
    const int jt0 = cc * CCT;
    sh8 bf = Bp[(size_t)jt0 * 64 + lane];
    f32x16 r;
#pragma unroll
    for (int q = 0; q < 16; ++q) r[q] = INF;

#pragma unroll 2
    for (int jt = 0; jt < CCT; ++jt) {
      int jn = (jt + 1 < CCT) ? (jt + 1) : jt;          // clamped prefetch
      sh8 bfn = Bp[(size_t)(jt0 + jn) * 64 + lane];
      f32x16 c = __builtin_amdgcn_mfma_f32_32x32x16_bf16(af, bf, zc, 0, 0, 0);
      r = __builtin_elementwise_min(r, c);
      float cv = c[0];
#pragma unroll
      for (int q = 1; q < 16; ++q) cv = fminf(cv, c[q]);
      cv = fminf(cv, __shfl_xor(cv, 32));
      if (lane < 32) atomicMin(&colmin[(jt << 5) | lane], flipf(cv));
      bf = bfn;
    }

#pragma unroll
    for (int q = 0; q < 16; ++q) {
      float v = r[q];
      v = fminf(v, __shfl_xor(v, 1));
      v = fminf(v, __shfl_xor(v, 2));
      v = fminf(v, __shfl_xor(v, 4));
      v = fminf(v, __shfl_xor(v, 8));
      v = fminf(v, __shfl_xor(v, 16));
      if ((lane & 31) == 0) {
        int row = rt * 32 + (q & 3) + 8 * (q >> 2) + 4 * (lane >> 5);
        atomicMin(outR + row, flipf(v));
      }
    }
    __syncthreads();
    for (int i = t; i < CCT * 32; i += BLK)
      atomicMin(outC + cc * (CCT * 32) + i, colmin[i]);
  } else {
    // ---- argmin pass (sv rows x tv cols) ----
    const int rem = bid - NB_F;
    const int rb = rem >> 4, cc = rem & 15;
    const int rt = rb * 4 + wave;
    const sh8* __restrict__ Ap = d.Asv;
    const sh8* __restrict__ Bp = d.Btv;
    sh8 af = Ap[(size_t)rt * 64 + lane];
    const int jt0 = cc * CCT;
    f32x16 m;
    float idx[16];
#pragma unroll
    for (int q = 0; q < 16; ++q) { m[q] = INF; idx[q] = 0.f; }
#pragma unroll 2
    for (int jt = 0; jt < CCT; ++jt) {
      sh8 bf = Bp[(size_t)(jt0 + jt) * 64 + lane];
      f32x16 c = __builtin_amdgcn_mfma_f32_32x32x16_bf16(af, bf, zc, 0, 0, 0);
      float colf = (float)((jt0 + jt) * 32 + (lane & 31));
#pragma unroll
      for (int q = 0; q < 16; ++q) {
        bool cm = c[q] < m[q];
        m[q] = cm ? c[q] : m[q];
        idx[q] = cm ? colf : idx[q];
      }
    }
    unsigned long long* __restrict__ out = d.min64;
#pragma unroll
    for (int q = 0; q < 16; ++q) {
      float v = m[q], ix = idx[q];
#pragma unroll
      for (int s = 0; s < 5; ++s) {
        int msk = 1 << s;
        float ov = __shfl_xor(v, msk);
        float oi = __shfl_xor(ix, msk);
        bool take = (ov < v) || (ov == v && oi < ix);
        v = take ? ov : v;
        ix = take ? oi : ix;
      }
      if ((lane & 31) == 0) {
        int row = rt * 32 + (q & 3) + 8 * (q >> 2) + 4 * (lane >> 5);
        unsigned long long packed =
            ((unsigned long long)flipf(v) << 32) | (unsigned)(int)ix;
        atomicMin(out + row, packed);
      }
    }
  }
}

// Fused tail. blockIdx.y: 0 smooth->acc[5], 1 normal->acc[6], 2-5 sqrt-sums
// ->acc[0..3]. Last block (ticket) computes the final scalar.
__global__ void __launch_bounds__(BLK) post_kernel(
    const float* __restrict__ sv, const float* __restrict__ sn,
    const float* __restrict__ tn,
    const float* __restrict__ nbr, const float* __restrict__ deg,
    const unsigned* __restrict__ minbase,
    const unsigned long long* __restrict__ min64,
    int n, int p, int g, int f, float* __restrict__ acc,
    int* __restrict__ cnt, float* __restrict__ out) {
  const int task = blockIdx.y;
  const int i = blockIdx.x * blockDim.x + threadIdx.x;
  float s = 0.f;
  int accIdx;
  if (task == 0) {
    accIdx = 5;
    if (i < n) {
      float dd = fmaxf(deg[i], 1.0f);
      float lx = nbr[3 * i + 0] / dd - sv[3 * i + 0];
      float ly = nbr[3 * i + 1] / dd - sv[3 * i + 1];
      float lz = nbr[3 * i + 2] / dd - sv[3 * i + 2];
      s = sqrtf(fmaf(lx, lx, fmaf(ly, ly, lz * lz)));
    }
  } else if (task == 1) {
    accIdx = 6;
    if (i < n) {
      int idx = (int)(min64[i] & 0xffffffffull);
      float sx = sn[3 * i], sy = sn[3 * i + 1], sz = sn[3 * i + 2];
      float tx = tn[3 * idx], ty = tn[3 * idx + 1], tz = tn[3 * idx + 2];
      float num = fmaf(sx, tx, fmaf(sy, ty, sz * tz));
      float ns = sqrtf(fmaf(sx, sx, fmaf(sy, sy, sz * sz)));
      float nt = sqrtf(fmaf(tx, tx, fmaf(ty, ty, tz * tz)));
      s = num / (fmaxf(ns, 1e-8f) * fmaxf(nt, 1e-8f));
    }
  } else {
    const int seg = task - 2;
    accIdx = seg;
    const int off = (seg == 0) ? 0 : (seg == 1) ? n : (seg == 2) ? (n + p) : (2 * n + p);
    const int cntN = (seg == 1) ? p : n;
    if (i < cntN) {
      float d2 = unflipf(minbase[off + i]);   // full d^2 from MFMA
      s = sqrtf(fmaxf(d2, 0.0f));
    }
  }
  s = wave_reduce_sum(s);
  if ((threadIdx.x & 63) == 0) atomicAdd(&acc[accIdx], s);

  __syncthreads();
  __threadfence();
  __shared__ int last;
  if (threadIdx.x == 0)
    last = (atomicAdd(cnt, 1) == (int)(gridDim.x * gridDim.y) - 1);
  __syncthreads();
  if (last && threadIdx.x == 0) {
    float a[7];
#pragma unroll
    for (int q = 0; q < 7; ++q) a[q] = atomicAdd(&acc[q], 0.0f);
    float lt = 0.5f * (a[0] / (float)n + a[1] / (float)p);
    float lg = 0.5f * (a[2] / (float)n + a[3] / (float)g);
    float chamfer = 0.7f * lt + 0.3f * lg;
    float edge = a[4] / (float)(3 * f);
    float smooth = a[5] / (float)n;
    float normal = 1.0f - a[6] / (float)n;
    out[0] = chamfer + 2.0f * edge + smooth + 0.5f * normal;
  }
}

extern "C" void kernel_launch(void* const* d_in, const int* in_sizes, int n_in,
                              void* d_out, int out_size, void* d_ws, size_t ws_size,
                              hipStream_t stream) {
  const float* sv = (const float*)d_in[0];
  const float* sn = (const float*)d_in[1];
  const float* tv = (const float*)d_in[2];
  const float* tn = (const float*)d_in[3];
  const float* tp = (const float*)d_in[4];
  const float* gp = (const float*)d_in[5];
  const int*   fc = (const int*)d_in[6];
  const int n = in_sizes[0] / 3;
  const int m = in_sizes[2] / 3;
  const int p = in_sizes[4] / 3;
  const int g = in_sizes[5] / 3;
  const int f = in_sizes[6] / 3;

  // ws layout: fragment packs (32 B per point per form), then scratch.
  char* w = (char*)d_ws;
  sh8* Asv = (sh8*)w; w += (size_t)n * 32;
  sh8* Btp = (sh8*)w; w += (size_t)p * 32;
  sh8* Bgp = (sh8*)w; w += (size_t)g * 32;
  sh8* Btv = (sh8*)w; w += (size_t)m * 32;
  unsigned long long* min64 = (unsigned long long*)w; w += (size_t)n * 8;
  unsigned* minbase = (unsigned*)w; w += (size_t)(n + p + n + g) * 4;
  float* nbr = (float*)w; w += (size_t)n * 3 * 4;   // zero region starts here
  float* deg = (float*)w; w += (size_t)n * 4;
  float* acc = (float*)w; w += 8 * 4;
  int* cnt = (int*)w;

  const int nmin = n + p + n + g;
  const int nz = n * 3 + n + 8 + 1;   // nbr, deg, acc, cnt

  init_ws_kernel<<<64, BLK, 0, stream>>>(Asv, Btp, Bgp, Btv, sv, tp, gp, tv,
                                         min64, n, minbase, nmin, nbr, nz, n);

  Desc d;
  d.Asv = Asv; d.Btp = Btp; d.Bgp = Bgp; d.Btv = Btv;
  d.minA_tp = minbase;
  d.minB_tp = minbase + n;
  d.minA_gt = minbase + n + p;
  d.minB_gt = minbase + 2 * n + p;
  d.min64 = min64;
  d.fc = fc; d.f = f; d.sv = sv;
  d.nbr = nbr; d.deg = deg; d.acc = acc;

  mega_kernel<<<NB_F + NB_A + NB_E, BLK, 0, stream>>>(d);

  dim3 tgrid((n + BLK - 1) / BLK, 6);
  post_kernel<<<tgrid, BLK, 0, stream>>>(sv, sn, tn, nbr, deg,
                                         minbase, min64, n, p, g, f,
                                         acc, cnt, (float*)d_out);
}